// Round 1
// baseline (5043.294 us; speedup 1.0000x reference)
//
#include <hip/hip_runtime.h>
#include <hip/hip_bf16.h>
#include <math.h>

#define T_LEN 827
#define M_ROWS 3308   // B*T
#define NLAYER 12

typedef __attribute__((ext_vector_type(4))) float f32x4;
typedef __attribute__((ext_vector_type(8))) short bf16x8;

__device__ __forceinline__ float gelu_f(float x) {
    return 0.5f * x * (1.0f + erff(x * 0.70710678118654752440f));
}

// ---------------- f32 -> bf16 conversion (x4 vectorized) ----------------
__global__ void cvt_kernel(const float* __restrict__ in, __hip_bfloat16* __restrict__ out, int n4) {
    int i = blockIdx.x * blockDim.x + threadIdx.x;
    if (i >= n4) return;
    float4 v = reinterpret_cast<const float4*>(in)[i];
    out[4*i+0] = __float2bfloat16(v.x);
    out[4*i+1] = __float2bfloat16(v.y);
    out[4*i+2] = __float2bfloat16(v.z);
    out[4*i+3] = __float2bfloat16(v.w);
}

__global__ void zero_kernel(float* __restrict__ p, int n) {
    for (int i = blockIdx.x * blockDim.x + threadIdx.x; i < n; i += gridDim.x * blockDim.x)
        p[i] = 0.f;
}

// ---------------- locality: z1 = gelu(p @ W1^T + b1), 3 ps x 4 batches x 60 ----------------
__global__ void loc_z1_kernel(const float* __restrict__ p1, const float* __restrict__ p2,
                              const float* __restrict__ p3, const float* __restrict__ W1,
                              const float* __restrict__ b1, float* __restrict__ z1) {
    for (int i = threadIdx.x; i < 720; i += 256) {
        int pi = i / 240, rem = i % 240, b = rem / 60, j = rem % 60;
        const float* p = (pi == 0) ? p1 : ((pi == 1) ? p2 : p3);
        float acc = b1[j];
        #pragma unroll
        for (int c = 0; c < 30; ++c) acc += p[b*30 + c] * W1[j*30 + c];
        z1[i] = gelu_f(acc);
    }
}

// ---------------- locality: z2 = z1 @ W2^T + b2 into h slices ----------------
// h is (4, 827, 827) f32, pre-zeroed. placements: (285,0) (571,0) (571,286)
__global__ void h_fill_kernel(const float* __restrict__ z1, const float* __restrict__ W2,
                              const float* __restrict__ b2, float* __restrict__ h) {
    __shared__ float z[720];
    int tid = threadIdx.x;
    for (int i = tid; i < 720; i += 256) z[i] = z1[i];
    __syncthreads();
    int j = blockIdx.x * 256 + tid;   // 0..65535
    float w[60];
    #pragma unroll
    for (int c = 0; c < 60; ++c) w[c] = W2[(size_t)j*60 + c];
    float bj = b2[j];
    int r = j >> 8, cc = j & 255;
    const int br[3] = {285, 571, 571};
    const int bc[3] = {0, 0, 286};
    #pragma unroll
    for (int pi = 0; pi < 3; ++pi) {
        for (int b = 0; b < 4; ++b) {
            float acc = bj;
            #pragma unroll
            for (int c = 0; c < 60; ++c) acc += z[pi*240 + b*60 + c] * w[c];
            h[(size_t)b*T_LEN*T_LEN + (size_t)(br[pi] + r)*T_LEN + bc[pi] + cc] = acc;
        }
    }
}

// ---------------- x = tok + role + time ----------------
__global__ void init_x_kernel(const float* __restrict__ dc, const float* __restrict__ z,
                              const float* __restrict__ frame, const float* __restrict__ cam,
                              const float* __restrict__ timeE, float* __restrict__ x) {
    int idx = blockIdx.x * 256 + threadIdx.x;   // M_ROWS*256 total
    int m = idx >> 8, c = idx & 255;
    int b = m / T_LEN, t = m % T_LEN;
    float tok = (t < 572) ? dc[((size_t)b*572 + t)*256 + c]
                          : z[((size_t)b*256 + (t - 572))*256 + c];
    float role;
    if      (t < 256) role = frame[t*256 + c];
    else if (t < 286) role = cam[(t-256)*256 + c];
    else if (t < 542) role = frame[(t-286)*256 + c];
    else if (t < 572) role = cam[(t-542)*256 + c];
    else              role = frame[(t-572)*256 + c];
    x[idx] = tok + role + timeE[t*256 + c];
}

// ---------------- row LayerNorm over C=256, bf16 out ----------------
__global__ __launch_bounds__(256) void ln_kernel(const float* __restrict__ x,
                                                 const float* __restrict__ w,
                                                 const float* __restrict__ b,
                                                 __hip_bfloat16* __restrict__ out) {
    int row = blockIdx.x, tid = threadIdx.x;
    float v = x[(size_t)row*256 + tid];
    float s = v;
    #pragma unroll
    for (int off = 32; off; off >>= 1) s += __shfl_down(s, off);
    __shared__ float red[4];
    if ((tid & 63) == 0) red[tid >> 6] = s;
    __syncthreads();
    float mean = (red[0] + red[1] + red[2] + red[3]) * (1.f/256.f);
    float d = v - mean;
    float s2 = d * d;
    #pragma unroll
    for (int off = 32; off; off >>= 1) s2 += __shfl_down(s2, off);
    __shared__ float red2[4];
    if ((tid & 63) == 0) red2[tid >> 6] = s2;
    __syncthreads();
    float var = (red2[0] + red2[1] + red2[2] + red2[3]) * (1.f/256.f);
    float rs = rsqrtf(var + 1e-5f);
    out[(size_t)row*256 + tid] = __float2bfloat16(d * rs * w[tid] + b[tid]);
}

// ---------------- generic MFMA GEMM: out(MxN) = act((A(MxK) @ W(NxK)^T + bias)*alpha) [+resid] ----------------
// A, W bf16 row-major; 64x64 block tile, BK=32, 4 waves (2x2), wave does 32x32 (2x2 frags).
// A/B frag: lane reads row (lane&15), 8 contiguous k at (lane>>4)*8.  C/D: col=lane&15, row=4*(lane>>4)+reg.
template<int ACT, bool OUTBF16, bool RESID>
__global__ __launch_bounds__(256) void gemm_kernel(const __hip_bfloat16* __restrict__ A,
                                                   const __hip_bfloat16* __restrict__ W,
                                                   const float* __restrict__ bias,
                                                   const float* __restrict__ resid,
                                                   void* __restrict__ out,
                                                   int M, int N, int K, float alpha) {
    __shared__ __hip_bfloat16 As[64][40];
    __shared__ __hip_bfloat16 Bs[64][40];
    const int tid = threadIdx.x;
    const int m0 = blockIdx.x * 64;
    const int n0 = blockIdx.y * 64;
    const int wid = tid >> 6, lane = tid & 63;
    const int wm = wid >> 1, wn = wid & 1;
    const int fr = lane & 15, fq = lane >> 4;
    const int srow = tid >> 2;         // 0..63
    const int scol = (tid & 3) * 8;    // 0,8,16,24

    f32x4 acc[2][2];
    #pragma unroll
    for (int mi = 0; mi < 2; ++mi)
        #pragma unroll
        for (int ni = 0; ni < 2; ++ni)
            acc[mi][ni] = (f32x4){0.f, 0.f, 0.f, 0.f};

    for (int k0 = 0; k0 < K; k0 += 32) {
        int gm = m0 + srow;
        uint4 av = make_uint4(0u, 0u, 0u, 0u);
        if (gm < M) av = *reinterpret_cast<const uint4*>(A + (size_t)gm*K + k0 + scol);
        *reinterpret_cast<uint4*>(&As[srow][scol]) = av;
        int gn = n0 + srow;   // N is always a multiple of 64
        uint4 bv = *reinterpret_cast<const uint4*>(W + (size_t)gn*K + k0 + scol);
        *reinterpret_cast<uint4*>(&Bs[srow][scol]) = bv;
        __syncthreads();
        bf16x8 af[2], bf[2];
        af[0] = *reinterpret_cast<const bf16x8*>(&As[wm*32 + fr][fq*8]);
        af[1] = *reinterpret_cast<const bf16x8*>(&As[wm*32 + 16 + fr][fq*8]);
        bf[0] = *reinterpret_cast<const bf16x8*>(&Bs[wn*32 + fr][fq*8]);
        bf[1] = *reinterpret_cast<const bf16x8*>(&Bs[wn*32 + 16 + fr][fq*8]);
        #pragma unroll
        for (int mi = 0; mi < 2; ++mi)
            #pragma unroll
            for (int ni = 0; ni < 2; ++ni)
                acc[mi][ni] = __builtin_amdgcn_mfma_f32_16x16x32_bf16(af[mi], bf[ni], acc[mi][ni], 0, 0, 0);
        __syncthreads();
    }

    #pragma unroll
    for (int mi = 0; mi < 2; ++mi) {
        #pragma unroll
        for (int ni = 0; ni < 2; ++ni) {
            int n = n0 + wn*32 + ni*16 + fr;
            float bv = bias ? bias[n] : 0.f;
            #pragma unroll
            for (int r = 0; r < 4; ++r) {
                int m = m0 + wm*32 + mi*16 + fq*4 + r;
                if (m >= M) continue;
                float v = (acc[mi][ni][r] + bv) * alpha;
                if (RESID) v += resid[(size_t)m*N + n];
                if (ACT == 1) v = gelu_f(v);
                if (OUTBF16) ((__hip_bfloat16*)out)[(size_t)m*N + n] = __float2bfloat16(v);
                else         ((float*)out)[(size_t)m*N + n] = v;
            }
        }
    }
}

// ---------------- attention: 4 q-rows per block, scores in LDS, f32 ----------------
// q (scaled), k, v: (B, T, H*DH) f32.  h: (B,T,T) f32.  y out bf16 (B,T,H*DH).
__global__ __launch_bounds__(256) void attn_kernel(const float* __restrict__ qm,
                                                   const float* __restrict__ km,
                                                   const float* __restrict__ vm,
                                                   const float* __restrict__ hbuf,
                                                   int adaptive,
                                                   __hip_bfloat16* __restrict__ y) {
    const int qg = blockIdx.x, hh = blockIdx.y, b = blockIdx.z;
    const int tid = threadIdx.x;
    const int q0 = qg * 4;
    const int nq = min(4, T_LEN - q0);
    const int nkmax = min(q0 + 4, T_LEN);
    __shared__ float qv[4][32];
    __shared__ float s[4][828];
    __shared__ float red[4][4];
    __shared__ float part[4][8][33];
    const size_t base = ((size_t)b * T_LEN) * 256 + hh * 32;

    if (tid < 128) {
        int qq = tid >> 5, d = tid & 31;
        if (qq < nq) qv[qq][d] = qm[base + (size_t)(q0 + qq)*256 + d];
    }
    __syncthreads();

    float lmax[4] = {-1e30f, -1e30f, -1e30f, -1e30f};
    for (int kk = tid; kk < nkmax; kk += 256) {
        const float* kp = km + base + (size_t)kk*256;
        float kv[32];
        #pragma unroll
        for (int d = 0; d < 32; ++d) kv[d] = kp[d];
        #pragma unroll
        for (int qq = 0; qq < 4; ++qq) {
            if (qq < nq && kk <= q0 + qq) {
                float acc = 0.f;
                #pragma unroll
                for (int d = 0; d < 32; ++d) acc += qv[qq][d] * kv[d];
                if (adaptive) acc += hbuf[((size_t)b*T_LEN + (q0 + qq))*T_LEN + kk];
                s[qq][kk] = acc;
                lmax[qq] = fmaxf(lmax[qq], acc);
            }
        }
    }
    #pragma unroll
    for (int qq = 0; qq < 4; ++qq) {
        float m = lmax[qq];
        #pragma unroll
        for (int off = 32; off; off >>= 1) m = fmaxf(m, __shfl_down(m, off));
        if ((tid & 63) == 0) red[qq][tid >> 6] = m;
    }
    __syncthreads();
    float mx[4];
    #pragma unroll
    for (int qq = 0; qq < 4; ++qq)
        mx[qq] = fmaxf(fmaxf(red[qq][0], red[qq][1]), fmaxf(red[qq][2], red[qq][3]));

    float lsum[4] = {0.f, 0.f, 0.f, 0.f};
    for (int kk = tid; kk < nkmax; kk += 256) {
        #pragma unroll
        for (int qq = 0; qq < 4; ++qq) {
            if (qq < nq && kk <= q0 + qq) {
                float e = __expf(s[qq][kk] - mx[qq]);
                s[qq][kk] = e;
                lsum[qq] += e;
            }
        }
    }
    __syncthreads();   // red reads done, s writes ordered before reuse
    #pragma unroll
    for (int qq = 0; qq < 4; ++qq) {
        float su = lsum[qq];
        #pragma unroll
        for (int off = 32; off; off >>= 1) su += __shfl_down(su, off);
        if ((tid & 63) == 0) red[qq][tid >> 6] = su;
    }
    __syncthreads();
    float inv[4];
    #pragma unroll
    for (int qq = 0; qq < 4; ++qq) {
        float su = red[qq][0] + red[qq][1] + red[qq][2] + red[qq][3];
        inv[qq] = (su > 0.f) ? (1.f / su) : 0.f;
    }

    int g = tid >> 5, d = tid & 31;
    float accq[4] = {0.f, 0.f, 0.f, 0.f};
    for (int kk = g; kk < nkmax; kk += 8) {
        float vv = vm[base + (size_t)kk*256 + d];
        #pragma unroll
        for (int qq = 0; qq < 4; ++qq)
            if (qq < nq && kk <= q0 + qq) accq[qq] += s[qq][kk] * vv;
    }
    #pragma unroll
    for (int qq = 0; qq < 4; ++qq) part[qq][g][d] = accq[qq];
    __syncthreads();
    if (tid < 128) {
        int qq = tid >> 5, dd = tid & 31;
        if (qq < nq) {
            float r = 0.f;
            #pragma unroll
            for (int gg = 0; gg < 8; ++gg) r += part[qq][gg][dd];
            y[base + (size_t)(q0 + qq)*256 + dd] = __float2bfloat16(r * inv[qq]);
        }
    }
}

extern "C" void kernel_launch(void* const* d_in, const int* in_sizes, int n_in,
                              void* d_out, int out_size, void* d_ws, size_t ws_size,
                              hipStream_t stream) {
    const float* dc    = (const float*)d_in[0];
    const float* zemb  = (const float*)d_in[1];
    const float* p1    = (const float*)d_in[2];
    const float* p2    = (const float*)d_in[3];
    const float* p3    = (const float*)d_in[4];
    const float* frame = (const float*)d_in[5];
    const float* cam   = (const float*)d_in[6];
    const float* timeE = (const float*)d_in[7];
    const float* locW1 = (const float*)d_in[8];
    const float* locb1 = (const float*)d_in[9];
    const float* locW2 = (const float*)d_in[10];
    const float* locb2 = (const float*)d_in[11];
    const float* ln1w  = (const float*)d_in[12];
    const float* ln1b  = (const float*)d_in[13];
    const float* Wq    = (const float*)d_in[14];
    const float* bq    = (const float*)d_in[15];
    const float* Wk    = (const float*)d_in[16];
    const float* bk    = (const float*)d_in[17];
    const float* Wv    = (const float*)d_in[18];
    const float* bv    = (const float*)d_in[19];
    const float* Wo    = (const float*)d_in[20];
    const float* bo    = (const float*)d_in[21];
    const float* ln2w  = (const float*)d_in[22];
    const float* ln2b  = (const float*)d_in[23];
    const float* W1p   = (const float*)d_in[24];
    const float* b1p   = (const float*)d_in[25];
    const float* W2p   = (const float*)d_in[26];
    const float* b2p   = (const float*)d_in[27];
    const float* lnfw  = (const float*)d_in[28];
    const float* lnfb  = (const float*)d_in[29];
    const float* headW = (const float*)d_in[30];

    char* wsb = (char*)d_ws;
    size_t off = 0;
    auto alloc = [&](size_t bytes) -> char* {
        char* p = wsb + off;
        off += (bytes + 255) & ~(size_t)255;
        return p;
    };
    __hip_bfloat16* wq_bf = (__hip_bfloat16*)alloc(12ull*65536*2);
    __hip_bfloat16* wk_bf = (__hip_bfloat16*)alloc(12ull*65536*2);
    __hip_bfloat16* wv_bf = (__hip_bfloat16*)alloc(12ull*65536*2);
    __hip_bfloat16* wo_bf = (__hip_bfloat16*)alloc(12ull*65536*2);
    __hip_bfloat16* w1_bf = (__hip_bfloat16*)alloc(12ull*262144*2);
    __hip_bfloat16* w2_bf = (__hip_bfloat16*)alloc(12ull*262144*2);
    __hip_bfloat16* wh_bf = (__hip_bfloat16*)alloc(16384ull*256*2);
    float* hbuf = (float*)alloc(4ull*T_LEN*T_LEN*4);
    float* x    = (float*)alloc((size_t)M_ROWS*256*4);
    __hip_bfloat16* xn  = (__hip_bfloat16*)alloc((size_t)M_ROWS*256*2);
    float* qb   = (float*)alloc((size_t)M_ROWS*256*4);
    float* kb   = (float*)alloc((size_t)M_ROWS*256*4);
    float* vb   = (float*)alloc((size_t)M_ROWS*256*4);
    __hip_bfloat16* yb  = (__hip_bfloat16*)alloc((size_t)M_ROWS*256*2);
    __hip_bfloat16* mid = (__hip_bfloat16*)alloc((size_t)M_ROWS*1024*2);
    float* z1   = (float*)alloc(720*4);

    // weight conversions
    cvt_kernel<<<768, 256, 0, stream>>>(Wq, wq_bf, 196608);
    cvt_kernel<<<768, 256, 0, stream>>>(Wk, wk_bf, 196608);
    cvt_kernel<<<768, 256, 0, stream>>>(Wv, wv_bf, 196608);
    cvt_kernel<<<768, 256, 0, stream>>>(Wo, wo_bf, 196608);
    cvt_kernel<<<3072, 256, 0, stream>>>(W1p, w1_bf, 786432);
    cvt_kernel<<<3072, 256, 0, stream>>>(W2p, w2_bf, 786432);
    cvt_kernel<<<4096, 256, 0, stream>>>(headW, wh_bf, 1048576);

    // locality bias h
    loc_z1_kernel<<<1, 256, 0, stream>>>(p1, p2, p3, locW1, locb1, z1);
    zero_kernel<<<2048, 256, 0, stream>>>(hbuf, 4*T_LEN*T_LEN);
    h_fill_kernel<<<256, 256, 0, stream>>>(z1, locW2, locb2, hbuf);

    // x init
    init_x_kernel<<<M_ROWS, 256, 0, stream>>>(dc, zemb, frame, cam, timeE, x);

    const float qscale = 0.17677669529663687f;  // 1/sqrt(32)
    dim3 g256((M_ROWS + 63)/64, 256/64);
    dim3 g1024((M_ROWS + 63)/64, 1024/64);

    for (int i = 0; i < NLAYER; ++i) {
        ln_kernel<<<M_ROWS, 256, 0, stream>>>(x, ln1w + i*256, ln1b + i*256, xn);
        gemm_kernel<0,false,false><<<g256, 256, 0, stream>>>(xn, wq_bf + (size_t)i*65536, bq + i*256, nullptr, qb, M_ROWS, 256, 256, qscale);
        gemm_kernel<0,false,false><<<g256, 256, 0, stream>>>(xn, wk_bf + (size_t)i*65536, bk + i*256, nullptr, kb, M_ROWS, 256, 256, 1.f);
        gemm_kernel<0,false,false><<<g256, 256, 0, stream>>>(xn, wv_bf + (size_t)i*65536, bv + i*256, nullptr, vb, M_ROWS, 256, 256, 1.f);
        attn_kernel<<<dim3(207, 8, 4), 256, 0, stream>>>(qb, kb, vb, hbuf, (i % 2 == 0) ? 1 : 0, yb);
        gemm_kernel<0,false,true><<<g256, 256, 0, stream>>>(yb, wo_bf + (size_t)i*65536, bo + i*256, x, x, M_ROWS, 256, 256, 1.f);
        ln_kernel<<<M_ROWS, 256, 0, stream>>>(x, ln2w + i*256, ln2b + i*256, xn);
        gemm_kernel<1,true,false><<<g1024, 256, 0, stream>>>(xn, w1_bf + (size_t)i*262144, b1p + i*1024, nullptr, mid, M_ROWS, 1024, 256, 1.f);
        gemm_kernel<0,false,true><<<g256, 256, 0, stream>>>(mid, w2_bf + (size_t)i*262144, b2p + i*256, x, x, M_ROWS, 256, 1024, 1.f);
    }

    // final LN + head
    ln_kernel<<<M_ROWS, 256, 0, stream>>>(x, lnfw, lnfb, xn);
    gemm_kernel<0,false,false><<<dim3(52, 256), 256, 0, stream>>>(xn, wh_bf, nullptr, nullptr, (float*)d_out, M_ROWS, 16384, 256, 1.f);
}

// Round 2
// 1173.051 us; speedup vs baseline: 4.2993x; 4.2993x over previous
//
#include <hip/hip_runtime.h>
#include <hip/hip_bf16.h>
#include <math.h>

#define T_LEN 827
#define M_ROWS 3308   // B*T
#define NLAYER 12

typedef __attribute__((ext_vector_type(4))) float f32x4;
typedef __attribute__((ext_vector_type(8))) short bf16x8;

__device__ __forceinline__ float gelu_f(float x) {
    return 0.5f * x * (1.0f + erff(x * 0.70710678118654752440f));
}

__device__ __forceinline__ short f2bf_s(float x) {
    __hip_bfloat16 h = __float2bfloat16(x);
    return *reinterpret_cast<short*>(&h);
}

// ---------------- f32 -> bf16 conversion (x4 vectorized) ----------------
__global__ void cvt_kernel(const float* __restrict__ in, __hip_bfloat16* __restrict__ out, int n4) {
    int i = blockIdx.x * blockDim.x + threadIdx.x;
    if (i >= n4) return;
    float4 v = reinterpret_cast<const float4*>(in)[i];
    out[4*i+0] = __float2bfloat16(v.x);
    out[4*i+1] = __float2bfloat16(v.y);
    out[4*i+2] = __float2bfloat16(v.z);
    out[4*i+3] = __float2bfloat16(v.w);
}

// Build stacked QKV weights (12, 768, 256) bf16 with qscale folded into Wq rows.
__global__ void prep_wqkv_kernel(const float* __restrict__ Wq, const float* __restrict__ Wk,
                                 const float* __restrict__ Wv, __hip_bfloat16* __restrict__ out) {
    int i = blockIdx.x * 256 + threadIdx.x;     // over 12*768*256/4
    if (i >= 12*768*64) return;
    int el = i * 4;
    int layer = el / (768*256);
    int rem = el % (768*256);
    int row = rem >> 8, col = rem & 255;
    const float* src;
    float sc = 1.f;
    if (row < 256)      { src = Wq + ((size_t)layer*256 + row)*256 + col; sc = 0.17677669529663687f; }
    else if (row < 512) { src = Wk + ((size_t)layer*256 + (row-256))*256 + col; }
    else                { src = Wv + ((size_t)layer*256 + (row-512))*256 + col; }
    float4 v = *reinterpret_cast<const float4*>(src);
    out[el+0] = __float2bfloat16(v.x * sc);
    out[el+1] = __float2bfloat16(v.y * sc);
    out[el+2] = __float2bfloat16(v.z * sc);
    out[el+3] = __float2bfloat16(v.w * sc);
}

__global__ void prep_bqkv_kernel(const float* __restrict__ bq, const float* __restrict__ bk,
                                 const float* __restrict__ bv, float* __restrict__ out) {
    int i = blockIdx.x * 256 + threadIdx.x;     // 12*768
    if (i >= 12*768) return;
    int layer = i / 768, row = i % 768;
    float v;
    if (row < 256)      v = bq[layer*256 + row] * 0.17677669529663687f;
    else if (row < 512) v = bk[layer*256 + (row-256)];
    else                v = bv[layer*256 + (row-512)];
    out[i] = v;
}

__global__ void zero_kernel(float* __restrict__ p, int n) {
    for (int i = blockIdx.x * blockDim.x + threadIdx.x; i < n; i += gridDim.x * blockDim.x)
        p[i] = 0.f;
}

// ---------------- locality: z1 = gelu(p @ W1^T + b1) ----------------
__global__ void loc_z1_kernel(const float* __restrict__ p1, const float* __restrict__ p2,
                              const float* __restrict__ p3, const float* __restrict__ W1,
                              const float* __restrict__ b1, float* __restrict__ z1) {
    for (int i = threadIdx.x; i < 720; i += 256) {
        int pi = i / 240, rem = i % 240, b = rem / 60, j = rem % 60;
        const float* p = (pi == 0) ? p1 : ((pi == 1) ? p2 : p3);
        float acc = b1[j];
        #pragma unroll
        for (int c = 0; c < 30; ++c) acc += p[b*30 + c] * W1[j*30 + c];
        z1[i] = gelu_f(acc);
    }
}

// ---------------- locality: z2 = z1 @ W2^T + b2 into h slices ----------------
__global__ void h_fill_kernel(const float* __restrict__ z1, const float* __restrict__ W2,
                              const float* __restrict__ b2, float* __restrict__ h) {
    __shared__ float z[720];
    int tid = threadIdx.x;
    for (int i = tid; i < 720; i += 256) z[i] = z1[i];
    __syncthreads();
    int j = blockIdx.x * 256 + tid;   // 0..65535
    float w[60];
    #pragma unroll
    for (int c = 0; c < 60; ++c) w[c] = W2[(size_t)j*60 + c];
    float bj = b2[j];
    int r = j >> 8, cc = j & 255;
    const int br[3] = {285, 571, 571};
    const int bc[3] = {0, 0, 286};
    #pragma unroll
    for (int pi = 0; pi < 3; ++pi) {
        for (int b = 0; b < 4; ++b) {
            float acc = bj;
            #pragma unroll
            for (int c = 0; c < 60; ++c) acc += z[pi*240 + b*60 + c] * w[c];
            h[(size_t)b*T_LEN*T_LEN + (size_t)(br[pi] + r)*T_LEN + bc[pi] + cc] = acc;
        }
    }
}

// ---------------- x = tok + role + time ----------------
__global__ void init_x_kernel(const float* __restrict__ dc, const float* __restrict__ z,
                              const float* __restrict__ frame, const float* __restrict__ cam,
                              const float* __restrict__ timeE, float* __restrict__ x) {
    int idx = blockIdx.x * 256 + threadIdx.x;
    int m = idx >> 8, c = idx & 255;
    int b = m / T_LEN, t = m % T_LEN;
    float tok = (t < 572) ? dc[((size_t)b*572 + t)*256 + c]
                          : z[((size_t)b*256 + (t - 572))*256 + c];
    float role;
    if      (t < 256) role = frame[t*256 + c];
    else if (t < 286) role = cam[(t-256)*256 + c];
    else if (t < 542) role = frame[(t-286)*256 + c];
    else if (t < 572) role = cam[(t-542)*256 + c];
    else              role = frame[(t-572)*256 + c];
    x[idx] = tok + role + timeE[t*256 + c];
}

// ---------------- row LayerNorm over C=256, bf16 out ----------------
__global__ __launch_bounds__(256) void ln_kernel(const float* __restrict__ x,
                                                 const float* __restrict__ w,
                                                 const float* __restrict__ b,
                                                 __hip_bfloat16* __restrict__ out) {
    int row = blockIdx.x, tid = threadIdx.x;
    float v = x[(size_t)row*256 + tid];
    float s = v;
    #pragma unroll
    for (int off = 32; off; off >>= 1) s += __shfl_down(s, off);
    __shared__ float red[4];
    if ((tid & 63) == 0) red[tid >> 6] = s;
    __syncthreads();
    float mean = (red[0] + red[1] + red[2] + red[3]) * (1.f/256.f);
    float d = v - mean;
    float s2 = d * d;
    #pragma unroll
    for (int off = 32; off; off >>= 1) s2 += __shfl_down(s2, off);
    __shared__ float red2[4];
    if ((tid & 63) == 0) red2[tid >> 6] = s2;
    __syncthreads();
    float var = (red2[0] + red2[1] + red2[2] + red2[3]) * (1.f/256.f);
    float rs = rsqrtf(var + 1e-5f);
    out[(size_t)row*256 + tid] = __float2bfloat16(d * rs * w[tid] + b[tid]);
}

// ---------------- generic MFMA GEMM ----------------
template<int ACT, bool OUTBF16, bool RESID>
__global__ __launch_bounds__(256) void gemm_kernel(const __hip_bfloat16* __restrict__ A,
                                                   const __hip_bfloat16* __restrict__ W,
                                                   const float* __restrict__ bias,
                                                   const float* __restrict__ resid,
                                                   void* __restrict__ out,
                                                   int M, int N, int K, float alpha) {
    __shared__ __hip_bfloat16 As[64][40];
    __shared__ __hip_bfloat16 Bs[64][40];
    const int tid = threadIdx.x;
    const int m0 = blockIdx.x * 64;
    const int n0 = blockIdx.y * 64;
    const int wid = tid >> 6, lane = tid & 63;
    const int wm = wid >> 1, wn = wid & 1;
    const int fr = lane & 15, fq = lane >> 4;
    const int srow = tid >> 2;
    const int scol = (tid & 3) * 8;

    f32x4 acc[2][2];
    #pragma unroll
    for (int mi = 0; mi < 2; ++mi)
        #pragma unroll
        for (int ni = 0; ni < 2; ++ni)
            acc[mi][ni] = (f32x4){0.f, 0.f, 0.f, 0.f};

    for (int k0 = 0; k0 < K; k0 += 32) {
        int gm = m0 + srow;
        uint4 av = make_uint4(0u, 0u, 0u, 0u);
        if (gm < M) av = *reinterpret_cast<const uint4*>(A + (size_t)gm*K + k0 + scol);
        *reinterpret_cast<uint4*>(&As[srow][scol]) = av;
        int gn = n0 + srow;
        uint4 bv = *reinterpret_cast<const uint4*>(W + (size_t)gn*K + k0 + scol);
        *reinterpret_cast<uint4*>(&Bs[srow][scol]) = bv;
        __syncthreads();
        bf16x8 af[2], bfr[2];
        af[0] = *reinterpret_cast<const bf16x8*>(&As[wm*32 + fr][fq*8]);
        af[1] = *reinterpret_cast<const bf16x8*>(&As[wm*32 + 16 + fr][fq*8]);
        bfr[0] = *reinterpret_cast<const bf16x8*>(&Bs[wn*32 + fr][fq*8]);
        bfr[1] = *reinterpret_cast<const bf16x8*>(&Bs[wn*32 + 16 + fr][fq*8]);
        #pragma unroll
        for (int mi = 0; mi < 2; ++mi)
            #pragma unroll
            for (int ni = 0; ni < 2; ++ni)
                acc[mi][ni] = __builtin_amdgcn_mfma_f32_16x16x32_bf16(af[mi], bfr[ni], acc[mi][ni], 0, 0, 0);
        __syncthreads();
    }

    #pragma unroll
    for (int mi = 0; mi < 2; ++mi) {
        #pragma unroll
        for (int ni = 0; ni < 2; ++ni) {
            int n = n0 + wn*32 + ni*16 + fr;
            float bv = bias ? bias[n] : 0.f;
            #pragma unroll
            for (int r = 0; r < 4; ++r) {
                int m = m0 + wm*32 + mi*16 + fq*4 + r;
                if (m >= M) continue;
                float v = (acc[mi][ni][r] + bv) * alpha;
                if (RESID) v += resid[(size_t)m*N + n];
                if (ACT == 1) v = gelu_f(v);
                if (OUTBF16) ((__hip_bfloat16*)out)[(size_t)m*N + n] = __float2bfloat16(v);
                else         ((float*)out)[(size_t)m*N + n] = v;
            }
        }
    }
}

// ---------------- MFMA flash attention ----------------
// qkv: (B*T, 768) bf16, q|k|v each 256 cols, qscale pre-folded into q.
// hbuf: (B, T, T) f32 bias (adaptive layers). y: (B*T, 256) bf16.
// Block: (qtile 64, head, batch); 4 waves, each owns 16 q rows.
template<int ADAPT>
__global__ __launch_bounds__(256) void attn_mfma_kernel(const __hip_bfloat16* __restrict__ qkv,
                                                        const float* __restrict__ hbuf,
                                                        __hip_bfloat16* __restrict__ y) {
    const int qi = blockIdx.x, hh = blockIdx.y, b = blockIdx.z;
    const int tid = threadIdx.x;
    const int w = tid >> 6, lane = tid & 63;
    const int c = lane & 15, g = lane >> 4;
    const int q0 = qi * 64;
    const int qw0 = q0 + w * 16;

    __shared__ short Ks[64][40];      // K tile: 64 krows x 32 dh (+pad)
    __shared__ short Vt[32][72];      // V tile transposed: 32 dh x 64 krows (+pad)
    __shared__ short Pw[4][16][72];   // per-wave P: 16 qrows x 64 k (+pad)

    // Q fragment: row qw0+c, 8 dh elems at g*8
    int qrow = qw0 + c; if (qrow > T_LEN-1) qrow = T_LEN-1;
    bf16x8 aq = *reinterpret_cast<const bf16x8*>(qkv + ((size_t)b*T_LEN + qrow)*768 + hh*32 + g*8);

    float m_r[4] = {-INFINITY, -INFINITY, -INFINITY, -INFINITY};
    float l_r[4] = {0.f, 0.f, 0.f, 0.f};
    f32x4 acc[2];
    acc[0] = (f32x4){0.f,0.f,0.f,0.f};
    acc[1] = (f32x4){0.f,0.f,0.f,0.f};

    const int nk = min(q0 + 64, T_LEN);
    const int srow = tid >> 2;          // 0..63
    const int scol8 = (tid & 3) * 8;    // 0,8,16,24

    for (int kb = 0; kb < nk; kb += 64) {
        // stage K and V(transposed)
        int krow = kb + srow; if (krow > T_LEN-1) krow = T_LEN-1;
        const __hip_bfloat16* kvbase = qkv + ((size_t)b*T_LEN + krow)*768 + hh*32 + scol8;
        bf16x8 kv8 = *reinterpret_cast<const bf16x8*>(kvbase + 256);
        *reinterpret_cast<bf16x8*>(&Ks[srow][scol8]) = kv8;
        bf16x8 vv8 = *reinterpret_cast<const bf16x8*>(kvbase + 512);
        #pragma unroll
        for (int jj = 0; jj < 8; ++jj) Vt[scol8 + jj][srow] = vv8[jj];
        __syncthreads();

        // QK^T: 4 MFMAs (k-subtiles of 16)
        f32x4 sc4[4];
        #pragma unroll
        for (int j = 0; j < 4; ++j) {
            bf16x8 bk = *reinterpret_cast<const bf16x8*>(&Ks[j*16 + c][g*8]);
            sc4[j] = __builtin_amdgcn_mfma_f32_16x16x32_bf16(aq, bk, (f32x4){0.f,0.f,0.f,0.f}, 0, 0, 0);
        }

        // mask + bias
        float sv[4][4];
        #pragma unroll
        for (int j = 0; j < 4; ++j) {
            int kk = kb + j*16 + c;
            #pragma unroll
            for (int r = 0; r < 4; ++r) {
                int qq = qw0 + g*4 + r;
                bool valid = (qq < T_LEN) && (kk <= qq);
                float s = sc4[j][r];
                if (ADAPT) s += valid ? hbuf[((size_t)b*T_LEN + qq)*T_LEN + kk] : 0.f;
                sv[j][r] = valid ? s : -INFINITY;
            }
        }

        // online softmax (row reduce over 16 lanes within group)
        float rm[4], rs[4], sf[4];
        #pragma unroll
        for (int r = 0; r < 4; ++r) {
            float m = fmaxf(fmaxf(sv[0][r], sv[1][r]), fmaxf(sv[2][r], sv[3][r]));
            #pragma unroll
            for (int msk = 1; msk <= 8; msk <<= 1) m = fmaxf(m, __shfl_xor(m, msk));
            float mn = fmaxf(m_r[r], m);
            sf[r] = __expf(m_r[r] - mn);
            m_r[r] = mn;
        }
        float p[4][4];
        #pragma unroll
        for (int r = 0; r < 4; ++r) {
            float su = 0.f;
            #pragma unroll
            for (int j = 0; j < 4; ++j) {
                float e = __expf(sv[j][r] - m_r[r]);
                p[j][r] = e;
                su += e;
            }
            #pragma unroll
            for (int msk = 1; msk <= 8; msk <<= 1) su += __shfl_xor(su, msk);
            rs[r] = su;
            l_r[r] = l_r[r] * sf[r] + rs[r];
            acc[0][r] *= sf[r];
            acc[1][r] *= sf[r];
        }

        // store P (bf16) to per-wave LDS
        #pragma unroll
        for (int j = 0; j < 4; ++j)
            #pragma unroll
            for (int r = 0; r < 4; ++r)
                Pw[w][g*4 + r][j*16 + c] = f2bf_s(p[j][r]);

        // PV: acc += P(16x64) @ V(64x32)
        #pragma unroll
        for (int kc = 0; kc < 2; ++kc) {
            bf16x8 ap = *reinterpret_cast<const bf16x8*>(&Pw[w][c][kc*32 + g*8]);
            #pragma unroll
            for (int dt = 0; dt < 2; ++dt) {
                bf16x8 bv = *reinterpret_cast<const bf16x8*>(&Vt[dt*16 + c][kc*32 + g*8]);
                acc[dt] = __builtin_amdgcn_mfma_f32_16x16x32_bf16(ap, bv, acc[dt], 0, 0, 0);
            }
        }
        __syncthreads();
    }

    // epilogue
    #pragma unroll
    for (int r = 0; r < 4; ++r) {
        int qq = qw0 + g*4 + r;
        if (qq >= T_LEN) continue;
        float inv = 1.f / l_r[r];
        #pragma unroll
        for (int dt = 0; dt < 2; ++dt)
            y[((size_t)b*T_LEN + qq)*256 + hh*32 + dt*16 + c] = __float2bfloat16(acc[dt][r] * inv);
    }
}

extern "C" void kernel_launch(void* const* d_in, const int* in_sizes, int n_in,
                              void* d_out, int out_size, void* d_ws, size_t ws_size,
                              hipStream_t stream) {
    const float* dc    = (const float*)d_in[0];
    const float* zemb  = (const float*)d_in[1];
    const float* p1    = (const float*)d_in[2];
    const float* p2    = (const float*)d_in[3];
    const float* p3    = (const float*)d_in[4];
    const float* frame = (const float*)d_in[5];
    const float* cam   = (const float*)d_in[6];
    const float* timeE = (const float*)d_in[7];
    const float* locW1 = (const float*)d_in[8];
    const float* locb1 = (const float*)d_in[9];
    const float* locW2 = (const float*)d_in[10];
    const float* locb2 = (const float*)d_in[11];
    const float* ln1w  = (const float*)d_in[12];
    const float* ln1b  = (const float*)d_in[13];
    const float* Wq    = (const float*)d_in[14];
    const float* bq    = (const float*)d_in[15];
    const float* Wk    = (const float*)d_in[16];
    const float* bk    = (const float*)d_in[17];
    const float* Wv    = (const float*)d_in[18];
    const float* bv    = (const float*)d_in[19];
    const float* Wo    = (const float*)d_in[20];
    const float* bo    = (const float*)d_in[21];
    const float* ln2w  = (const float*)d_in[22];
    const float* ln2b  = (const float*)d_in[23];
    const float* W1p   = (const float*)d_in[24];
    const float* b1p   = (const float*)d_in[25];
    const float* W2p   = (const float*)d_in[26];
    const float* b2p   = (const float*)d_in[27];
    const float* lnfw  = (const float*)d_in[28];
    const float* lnfb  = (const float*)d_in[29];
    const float* headW = (const float*)d_in[30];

    char* wsb = (char*)d_ws;
    size_t off = 0;
    auto alloc = [&](size_t bytes) -> char* {
        char* p = wsb + off;
        off += (bytes + 255) & ~(size_t)255;
        return p;
    };
    __hip_bfloat16* wqkv_bf = (__hip_bfloat16*)alloc(12ull*768*256*2);
    float*          bqkv    = (float*)alloc(12ull*768*4);
    __hip_bfloat16* wo_bf = (__hip_bfloat16*)alloc(12ull*65536*2);
    __hip_bfloat16* w1_bf = (__hip_bfloat16*)alloc(12ull*262144*2);
    __hip_bfloat16* w2_bf = (__hip_bfloat16*)alloc(12ull*262144*2);
    __hip_bfloat16* wh_bf = (__hip_bfloat16*)alloc(16384ull*256*2);
    float* hbuf = (float*)alloc(4ull*T_LEN*T_LEN*4);
    float* x    = (float*)alloc((size_t)M_ROWS*256*4);
    __hip_bfloat16* xn   = (__hip_bfloat16*)alloc((size_t)M_ROWS*256*2);
    __hip_bfloat16* qkvb = (__hip_bfloat16*)alloc((size_t)M_ROWS*768*2);
    __hip_bfloat16* yb   = (__hip_bfloat16*)alloc((size_t)M_ROWS*256*2);
    __hip_bfloat16* mid  = (__hip_bfloat16*)alloc((size_t)M_ROWS*1024*2);
    float* z1   = (float*)alloc(720*4);

    // weight prep
    prep_wqkv_kernel<<<(12*768*64 + 255)/256, 256, 0, stream>>>(Wq, Wk, Wv, wqkv_bf);
    prep_bqkv_kernel<<<36, 256, 0, stream>>>(bq, bk, bv, bqkv);
    cvt_kernel<<<768, 256, 0, stream>>>(Wo, wo_bf, 196608);
    cvt_kernel<<<3072, 256, 0, stream>>>(W1p, w1_bf, 786432);
    cvt_kernel<<<3072, 256, 0, stream>>>(W2p, w2_bf, 786432);
    cvt_kernel<<<4096, 256, 0, stream>>>(headW, wh_bf, 1048576);

    // locality bias h
    loc_z1_kernel<<<1, 256, 0, stream>>>(p1, p2, p3, locW1, locb1, z1);
    zero_kernel<<<2048, 256, 0, stream>>>(hbuf, 4*T_LEN*T_LEN);
    h_fill_kernel<<<256, 256, 0, stream>>>(z1, locW2, locb2, hbuf);

    // x init
    init_x_kernel<<<M_ROWS, 256, 0, stream>>>(dc, zemb, frame, cam, timeE, x);

    dim3 g256((M_ROWS + 63)/64, 256/64);
    dim3 g768((M_ROWS + 63)/64, 768/64);
    dim3 g1024((M_ROWS + 63)/64, 1024/64);
    dim3 gattn(13, 8, 4);

    for (int i = 0; i < NLAYER; ++i) {
        ln_kernel<<<M_ROWS, 256, 0, stream>>>(x, ln1w + i*256, ln1b + i*256, xn);
        gemm_kernel<0,true,false><<<g768, 256, 0, stream>>>(xn, wqkv_bf + (size_t)i*768*256, bqkv + i*768, nullptr, qkvb, M_ROWS, 768, 256, 1.f);
        if (i % 2 == 0) attn_mfma_kernel<1><<<gattn, 256, 0, stream>>>(qkvb, hbuf, yb);
        else            attn_mfma_kernel<0><<<gattn, 256, 0, stream>>>(qkvb, hbuf, yb);
        gemm_kernel<0,false,true><<<g256, 256, 0, stream>>>(yb, wo_bf + (size_t)i*65536, bo + i*256, x, x, M_ROWS, 256, 256, 1.f);
        ln_kernel<<<M_ROWS, 256, 0, stream>>>(x, ln2w + i*256, ln2b + i*256, xn);
        gemm_kernel<1,true,false><<<g1024, 256, 0, stream>>>(xn, w1_bf + (size_t)i*262144, b1p + i*1024, nullptr, mid, M_ROWS, 1024, 256, 1.f);
        gemm_kernel<0,false,true><<<g256, 256, 0, stream>>>(mid, w2_bf + (size_t)i*262144, b2p + i*256, x, x, M_ROWS, 256, 1024, 1.f);
    }

    // final LN + head
    ln_kernel<<<M_ROWS, 256, 0, stream>>>(x, lnfw, lnfb, xn);
    gemm_kernel<0,false,false><<<dim3(52, 256), 256, 0, stream>>>(xn, wh_bf, nullptr, nullptr, (float*)d_out, M_ROWS, 16384, 256, 1.f);
}